// Round 4
// baseline (1362.857 us; speedup 1.0000x reference)
//
#include <hip/hip_runtime.h>
#include <hip/hip_bf16.h>
#include <math.h>

// Problem constants (from reference)
#define B_SZ 128
#define T_SZ 65536
#define F_FR 4095          // (T - 32)/16 + 1
#define GHID 64            // GRU hidden
#define HID 8
#define CHUNK 256          // fast-scan chunk length
#define NCH (T_SZ / CHUNK) // 256 chunks

typedef _Float16 half8 __attribute__((ext_vector_type(8)));
typedef float f32x4 __attribute__((ext_vector_type(4)));

#define L2E 1.4426950408889634f

static __device__ __forceinline__ float frcp(float v) {
#if __has_builtin(__builtin_amdgcn_rcpf)
    return __builtin_amdgcn_rcpf(v);
#else
    return 1.0f / v;
#endif
}
static __device__ __forceinline__ float fexp2(float v) {
#if __has_builtin(__builtin_amdgcn_exp2f)
    return __builtin_amdgcn_exp2f(v);
#else
    return exp2f(v);
#endif
}
__device__ __forceinline__ float sigm(float xv) { return frcp(1.0f + fexp2(-L2E * xv)); }

#define FSTR 68   // H row stride (f32): 68%32=4 -> benign banking (measured r1: ~2%)
#define XSTR 34   // x-stage row stride (f32); reads are wave-broadcast anyway

// ---------------- Pass 1: per-frame GRU via MFMA ----------------
// Round-3 restructure (fixes r2's VGPR=112 remat/spill of the 96-reg W frags):
//  * W_hh^T (f16, pre-scaled) staged ONCE per block in LDS, FRAG-MAJOR:
//    WF[f=2n+c][lane][8 f16] -> per-step B-frag read = 1 conflict-free
//    ds_read_b128 (consecutive lanes -> consecutive 16B).
//  * Each wave now owns 32 sequences (two 16-row M-tiles) so each B-frag
//    read feeds 2 MFMAs -> W LDS traffic amortized 2x.
//  * H[32][FSTR] f32 per-wave, SINGLE buffer, no barriers in t-loop:
//    same-wave DS ops are in-order; per-lane read-then-write to the same
//    LDS object keeps program order (may-alias), so reads see old h.
//  * amdgpu_waves_per_eu(2,2) forces the allocator to budget ~256 VGPRs
//    (launch_bounds' 2nd arg is only a min -> r2 compiler chose 112 and
//    rematerialized W every step = the 2.7x VALU inflation).
// Math identical to r2 (verified): W rows pre-scaled by -log2e (R/Z) and
// 2log2e (N); b_hh_n kept INSIDE the r-product; H fed hi/lo f16.
__global__ __launch_bounds__(256) __attribute__((amdgpu_waves_per_eu(2, 2)))
void gru_mfma(
    const float* __restrict__ x, const float* __restrict__ w_ih,
    const float* __restrict__ w_hh, const float* __restrict__ b_ih,
    const float* __restrict__ b_hh, const float* __restrict__ w_sl,
    const float* __restrict__ b_sl, float* __restrict__ ag)
{
    __shared__ _Float16 wlds[24 * 64 * 8];                 // 24 KB frag-major W
    __shared__ float hx[4][32 * FSTR + 32 * XSTR];         // per-wave H | X: 52.2 KB
    const int tid  = threadIdx.x;
    const int wv   = tid >> 6;
    const int lane = tid & 63;
    const int c16  = lane & 15;   // B-col (gate-in-tile) / A-row (seq-in-Mtile)
    const int g    = lane >> 4;   // k-group / C row-group
    float* hb = &hx[wv][0];
    float* xs = hb + 32 * FSTR;
    const int tile = ((int)blockIdx.x * 4 + wv) * 32;      // 32 seqs per wave

    // ---- cooperative W stage: 24 frags, 6 per wave ----
#pragma unroll
    for (int f = 0; f < 24; f += 4) {
        const int fi = f + wv;
        const int n = fi >> 1, c = fi & 1;
        const float sc = (n < 8) ? -L2E : (2.0f * L2E);
        const float* wp = w_hh + (16 * n + c16) * 64 + 32 * c + 8 * g;
        const float4 q0 = *(const float4*)wp;
        const float4 q1 = *(const float4*)(wp + 4);
        half8 w8;
        w8[0] = (_Float16)(sc * q0.x); w8[1] = (_Float16)(sc * q0.y);
        w8[2] = (_Float16)(sc * q0.z); w8[3] = (_Float16)(sc * q0.w);
        w8[4] = (_Float16)(sc * q1.x); w8[5] = (_Float16)(sc * q1.y);
        w8[6] = (_Float16)(sc * q1.z); w8[7] = (_Float16)(sc * q1.w);
        *(half8*)(wlds + (fi * 64 + lane) * 8) = w8;
    }

    // ---- per-lane gate constants (8 gates j = c16 + 16m over both M-tiles share) ----
    float wiR[4], wiZ[4], wiN[4], bR[4], bZ[4], biN[4], bhN[4];
#pragma unroll
    for (int m = 0; m < 4; ++m) {
        const int j = c16 + 16 * m;
        wiR[m] = -L2E * w_ih[j];
        wiZ[m] = -L2E * w_ih[64 + j];
        wiN[m] = 2.0f * L2E * w_ih[128 + j];
        bR[m]  = -L2E * (b_ih[j] + b_hh[j]);
        bZ[m]  = -L2E * (b_ih[64 + j] + b_hh[64 + j]);
        biN[m] = 2.0f * L2E * b_ih[128 + j];          // additive part only
        bhN[m] = 2.0f * L2E * b_hh[128 + j];          // multiplied by r
    }

    // ---- stage x[32 seq][32 t]; zero H ----
    {
        const int sl = lane & 31, half = lane >> 5;
        const int s = tile + sl;
        const int b = s / F_FR;
        const int f = s % F_FR;
        const float* xp = x + (long)b * T_SZ + f * 16 + 16 * half;
        const float4 p0 = *(const float4*)xp;
        const float4 p1 = *(const float4*)(xp + 4);
        const float4 p2 = *(const float4*)(xp + 8);
        const float4 p3 = *(const float4*)(xp + 12);
        float* xd = xs + sl * XSTR + 16 * half;
        *(float4*)(xd)      = p0;  *(float4*)(xd + 4)  = p1;
        *(float4*)(xd + 8)  = p2;  *(float4*)(xd + 12) = p3;
    }
    for (int idx = lane; idx < 32 * FSTR; idx += 64) hb[idx] = 0.0f;
    __syncthreads();   // W frags cross-wave; H/X are per-wave

    const f32x4 zz = {0.0f, 0.0f, 0.0f, 0.0f};
    float ho[2][4][4];
#pragma unroll
    for (int mt = 0; mt < 2; ++mt)
#pragma unroll
        for (int m = 0; m < 4; ++m)
#pragma unroll
            for (int r = 0; r < 4; ++r) ho[mt][m][r] = 0.0f;

#pragma unroll 1
    for (int t = 0; t < 32; ++t) {
        // A-frags (H hi/lo) for both M-tiles
        half8 ah[2][2], al[2][2];
#pragma unroll
        for (int mt = 0; mt < 2; ++mt)
#pragma unroll
        for (int c = 0; c < 2; ++c) {
            const float* rp = hb + (c16 + 16 * mt) * FSTR + 32 * c + 8 * g;
            const float4 u0 = *(const float4*)rp;
            const float4 u1 = *(const float4*)(rp + 4);
            const float fv[8] = {u0.x, u0.y, u0.z, u0.w, u1.x, u1.y, u1.z, u1.w};
#pragma unroll
            for (int e = 0; e < 8; ++e) {
                const _Float16 hi = (_Float16)fv[e];
                ah[mt][c][e] = hi;
                al[mt][c][e] = (_Float16)(fv[e] - (float)hi);
            }
        }

        f32x4 acc[2][12];
#pragma unroll
        for (int n = 0; n < 12; ++n) {
            const half8 b0 = *(const half8*)(wlds + ((2 * n + 0) * 64 + lane) * 8);
            const half8 b1 = *(const half8*)(wlds + ((2 * n + 1) * 64 + lane) * 8);
#pragma unroll
            for (int mt = 0; mt < 2; ++mt) {
                f32x4 a = __builtin_amdgcn_mfma_f32_16x16x32_f16(ah[mt][0], b0, zz, 0, 0, 0);
                a = __builtin_amdgcn_mfma_f32_16x16x32_f16(al[mt][0], b0, a, 0, 0, 0);
                a = __builtin_amdgcn_mfma_f32_16x16x32_f16(ah[mt][1], b1, a, 0, 0, 0);
                acc[mt][n] = __builtin_amdgcn_mfma_f32_16x16x32_f16(al[mt][1], b1, a, 0, 0, 0);
            }
        }

#pragma unroll
        for (int mt = 0; mt < 2; ++mt) {
            float xt4[4];
#pragma unroll
            for (int r = 0; r < 4; ++r) xt4[r] = xs[(4 * g + r + 16 * mt) * XSTR + t];
#pragma unroll
            for (int m = 0; m < 4; ++m) {
                const int jm = c16 + 16 * m;
#pragma unroll
                for (int r = 0; r < 4; ++r) {
                    // uR = -log2e*(ir+hr) ; r = 1/(1+2^uR) = sigmoid(ir+hr)
                    const float uR = fmaf(xt4[r], wiR[m], bR[m]) + acc[mt][m][r];
                    const float rr = frcp(1.0f + fexp2(uR));
                    const float uZ = fmaf(xt4[r], wiZ[m], bZ[m]) + acc[mt][4 + m][r];
                    const float zf = frcp(1.0f + fexp2(uZ));
                    // uN = 2log2e*(inn + r*(Wn.h + b_hh_n)) ; n = tanh(.)
                    const float uN = fmaf(rr, acc[mt][8 + m][r] + bhN[m],
                                          fmaf(xt4[r], wiN[m], biN[m]));
                    const float nn = fmaf(-2.0f, frcp(1.0f + fexp2(uN)), 1.0f);
                    const float hnew = fmaf(zf, ho[mt][m][r] - nn, nn);
                    ho[mt][m][r] = hnew;
                    hb[(4 * g + r + 16 * mt) * FSTR + jm] = hnew;
                }
            }
        }
    }

    // ---- epilogue: eps = hT @ w_sl^T + b_sl, per M-tile ----
    half8 wsl[2];
#pragma unroll
    for (int c = 0; c < 2; ++c) {
        const float4 q0 = *(const float4*)(w_sl + c16 * 64 + 32 * c + 8 * g);
        const float4 q1 = *(const float4*)(w_sl + c16 * 64 + 32 * c + 8 * g + 4);
        wsl[c][0] = (_Float16)q0.x; wsl[c][1] = (_Float16)q0.y;
        wsl[c][2] = (_Float16)q0.z; wsl[c][3] = (_Float16)q0.w;
        wsl[c][4] = (_Float16)q1.x; wsl[c][5] = (_Float16)q1.y;
        wsl[c][6] = (_Float16)q1.z; wsl[c][7] = (_Float16)q1.w;
    }
    const float bs = b_sl[c16];
#pragma unroll
    for (int mt = 0; mt < 2; ++mt) {
        half8 fh[2], fl[2];
#pragma unroll
        for (int c = 0; c < 2; ++c) {
            const float* rp = hb + (c16 + 16 * mt) * FSTR + 32 * c + 8 * g;
            const float4 u0 = *(const float4*)rp;
            const float4 u1 = *(const float4*)(rp + 4);
            const float fv[8] = {u0.x, u0.y, u0.z, u0.w, u1.x, u1.y, u1.z, u1.w};
#pragma unroll
            for (int e = 0; e < 8; ++e) {
                const _Float16 hi = (_Float16)fv[e];
                fh[c][e] = hi;
                fl[c][e] = (_Float16)(fv[e] - (float)hi);
            }
        }
        f32x4 ec = __builtin_amdgcn_mfma_f32_16x16x32_f16(fh[0], wsl[0], zz, 0, 0, 0);
        ec = __builtin_amdgcn_mfma_f32_16x16x32_f16(fl[0], wsl[0], ec, 0, 0, 0);
        ec = __builtin_amdgcn_mfma_f32_16x16x32_f16(fh[1], wsl[1], ec, 0, 0, 0);
        ec = __builtin_amdgcn_mfma_f32_16x16x32_f16(fl[1], wsl[1], ec, 0, 0, 0);
#pragma unroll
        for (int r = 0; r < 4; ++r) {
            float e = ec[r] + bs;
            if (c16 < 8) e = sigm(e);        // A_s = sigmoid(eps[:8]); g_s raw
            ag[(long)(tile + 16 * mt + 4 * g + r) * 16 + c16] = e;
        }
    }
}

// ---------------- Pass 2a: fast-scan chunk summaries ----------------
__global__ __launch_bounds__(256) void fast_chunk(
    const float* __restrict__ x, const float* __restrict__ ag,
    const float* __restrict__ w_in,
    float* __restrict__ chP, float* __restrict__ chH)
{
    const int tid = blockIdx.x * 256 + threadIdx.x;  // tid = b*NCH + c
    const int b = tid / NCH, c = tid % NCH;
    float h[HID], P[HID];
#pragma unroll
    for (int i = 0; i < HID; ++i) { h[i] = 0.0f; P[i] = 1.0f; }
    const float* xp = x + (long)b * T_SZ + c * CHUNK;

#pragma unroll 1
    for (int g = 0; g < CHUNK / 16; ++g) {
        const int t0 = c * CHUNK + g * 16;
        int fr = t0 / 16 - 1; fr = max(0, min(F_FR - 1, fr));
        const float4* agp = (const float4*)(ag + ((long)b * F_FR + fr) * 16);
        const float4 a0 = agp[0], a1 = agp[1], g0 = agp[2], g1 = agp[3];
        const float A[HID]  = {a0.x, a0.y, a0.z, a0.w, a1.x, a1.y, a1.z, a1.w};
        const float Gv[HID] = {g0.x, g0.y, g0.z, g0.w, g1.x, g1.y, g1.z, g1.w};
        float wg[HID];
#pragma unroll
        for (int i = 0; i < HID; ++i) wg[i] = w_in[i] * Gv[i];
#pragma unroll
        for (int tt = 0; tt < 16; ++tt) {
            const float xt = xp[g * 16 + tt];
#pragma unroll
            for (int i = 0; i < HID; ++i) h[i] = fmaf(A[i], h[i], xt * wg[i]);
        }
#pragma unroll
        for (int i = 0; i < HID; ++i) {
            const float a2 = A[i] * A[i]; const float a4 = a2 * a2; const float a8 = a4 * a4;
            P[i] *= a8 * a8;
        }
    }
    float* pp = chP + (long)tid * HID;
    float* hp = chH + (long)tid * HID;
#pragma unroll
    for (int i = 0; i < HID; ++i) { pp[i] = P[i]; hp[i] = h[i]; }
}

// ---------------- Pass 2b: scan over chunks ----------------
__global__ __launch_bounds__(256) void chunk_scan(
    const float* __restrict__ chP, const float* __restrict__ chH,
    float* __restrict__ st)
{
    const int tid = blockIdx.x * 256 + threadIdx.x;
    if (tid >= B_SZ * HID) return;
    const int b = tid / HID, i = tid % HID;
    float h = 0.0f;
#pragma unroll 1
    for (int c = 0; c < NCH; ++c) {
        const long idx = ((long)b * NCH + c) * HID + i;
        st[idx] = h;
        h = fmaf(chP[idx], h, chH[idx]);
    }
}

// ---------------- Pass 2c: apply + output ----------------
__global__ __launch_bounds__(256) void fast_apply(
    const float* __restrict__ x, const float* __restrict__ ag,
    const float* __restrict__ w_in, const float* __restrict__ w_out,
    const float* __restrict__ st, float* __restrict__ y)
{
    const int tid = blockIdx.x * 256 + threadIdx.x;  // tid = b*NCH + c
    const int b = tid / NCH, c = tid % NCH;
    float h[HID];
    const float* sp = st + (long)tid * HID;
#pragma unroll
    for (int i = 0; i < HID; ++i) h[i] = sp[i];
    float wo[HID];
#pragma unroll
    for (int i = 0; i < HID; ++i) wo[i] = w_out[i];
    const float* xp = x + (long)b * T_SZ + c * CHUNK;
    float* yp = y + (long)b * T_SZ + c * CHUNK;

#pragma unroll 1
    for (int g = 0; g < CHUNK / 16; ++g) {
        const int t0 = c * CHUNK + g * 16;
        int fr = t0 / 16 - 1; fr = max(0, min(F_FR - 1, fr));
        const float4* agp = (const float4*)(ag + ((long)b * F_FR + fr) * 16);
        const float4 a0 = agp[0], a1 = agp[1], g0 = agp[2], g1 = agp[3];
        const float A[HID]  = {a0.x, a0.y, a0.z, a0.w, a1.x, a1.y, a1.z, a1.w};
        const float Gv[HID] = {g0.x, g0.y, g0.z, g0.w, g1.x, g1.y, g1.z, g1.w};
        float wg[HID];
#pragma unroll
        for (int i = 0; i < HID; ++i) wg[i] = w_in[i] * Gv[i];
#pragma unroll
        for (int tt = 0; tt < 16; ++tt) {
            const float xt = xp[g * 16 + tt];
            float acc = 0.0f;
#pragma unroll
            for (int i = 0; i < HID; ++i) {
                h[i] = fmaf(A[i], h[i], xt * wg[i]);
                acc = fmaf(h[i], wo[i], acc);
            }
            yp[g * 16 + tt] = acc;
        }
    }
}

extern "C" void kernel_launch(void* const* d_in, const int* in_sizes, int n_in,
                              void* d_out, int out_size, void* d_ws, size_t ws_size,
                              hipStream_t stream) {
    const float* x    = (const float*)d_in[0];
    const float* w_in = (const float*)d_in[1];
    const float* w_out= (const float*)d_in[2];
    const float* w_ih = (const float*)d_in[3];
    const float* w_hh = (const float*)d_in[4];
    const float* b_ih = (const float*)d_in[5];
    const float* b_hh = (const float*)d_in[6];
    const float* w_sl = (const float*)d_in[7];
    const float* b_sl = (const float*)d_in[8];
    float* y = (float*)d_out;

    // Workspace layout (floats): ag[B][F][16] | chP[B][NCH][8] | chH | st
    float* ag  = (float*)d_ws;
    size_t off = (size_t)B_SZ * F_FR * 16;            // 8,386,560
    float* chP = ag + off;
    float* chH = chP + (size_t)B_SZ * NCH * HID;      // 262,144 each
    float* st  = chH + (size_t)B_SZ * NCH * HID;      // total ~36.7 MB

    // 524,160 seqs = 4095 blocks x 4 waves x 32 seqs
    gru_mfma<<<4095, 256, 0, stream>>>(x, w_ih, w_hh, b_ih, b_hh, w_sl, b_sl, ag);
    fast_chunk<<<(B_SZ * NCH) / 256, 256, 0, stream>>>(x, ag, w_in, chP, chH);
    chunk_scan<<<(B_SZ * HID + 255) / 256, 256, 0, stream>>>(chP, chH, st);
    fast_apply<<<(B_SZ * NCH) / 256, 256, 0, stream>>>(x, ag, w_in, w_out, st, y);
}